// Round 7
// baseline (9199.628 us; speedup 1.0000x reference)
//
#include <hip/hip_runtime.h>
#include <hip/hip_fp16.h>

// Persistent 2D-LSTM, tagged ring + 4-chain latency interleave.
// B=64, NC=512, T=1024, K=1216 = [x 0..191 | h(t-32) 192..703 | h(t-1) 704..1215].
// 64 WGs x 512 thr (8 waves). WG w owns channels w*8..w*8+7 (x4 gates = 32 cols).
// Each WG serves 4 independent batch-chains (g=0..3, 16 batches each) round-robin;
// chain g's h(t) is published at sub-step (t,g), prefetched 2 sub-steps later,
// consumed at (t+1,g) -- the MALL round-trip hides under other chains' compute.
// h ring: fp16 [slot 64][g 4][b 16][ch 512]; u64 = 4 ch; fp16 LSB = generation
// parity ((t>>6)&1). Ring pre-memset 0x01 (parity 1) != gen-0 parity 0.

typedef __attribute__((ext_vector_type(8))) _Float16 half8;
typedef __attribute__((ext_vector_type(4))) float f32x4;
typedef unsigned long long u64;

#define T_ 1024

#define LDS_W    77824              // 38 chunks * 2 tiles * 64 lanes * 16B
#define LDS_PSM  33792              // f32 [2][8][16][33]
#define LDS_CST  2048               // f32 [4][128]
#define LDS_ALL  (LDS_W + LDS_PSM + LDS_CST)

extern __shared__ char smem[];

__global__ __launch_bounds__(512, 2) void lstm_persist(
    const float* __restrict__ x, const float* __restrict__ Wih,
    const float* __restrict__ Whh, const float* __restrict__ bih,
    const float* __restrict__ bhh, float* __restrict__ out,
    u64* ring)
{
    _Float16* Wsm = (_Float16*)smem;
    float*    Psm = (float*)(smem + LDS_W);
    float*    cst = (float*)(smem + LDS_W + LDS_PSM);   // [4][128]

    const int tid = threadIdx.x;
    const int l   = tid & 63, wv = tid >> 6;
    const int l15 = l & 15,  l4 = l >> 4;
    const int w   = blockIdx.x;        // 0..63 channel WG

    // ---- weights fp32 -> fp16 fragments in LDS (once) ----
    for (int p = wv; p < 76; p += 8) {
        const int c = p >> 1, nb = p & 1;
        const int rj = (l15 & 3) * 512 + w * 8 + nb * 4 + (l15 >> 2);
        const int k  = c * 32 + l4 * 8;
        const float* src = (c < 22) ? (Wih + (size_t)rj * 704 + k)
                                    : (Whh + (size_t)rj * 512 + (k - 704));
        float4 v0 = ((const float4*)src)[0];
        float4 v1 = ((const float4*)src)[1];
        half8 hb;
        hb[0]=(_Float16)v0.x; hb[1]=(_Float16)v0.y; hb[2]=(_Float16)v0.z; hb[3]=(_Float16)v0.w;
        hb[4]=(_Float16)v1.x; hb[5]=(_Float16)v1.y; hb[6]=(_Float16)v1.z; hb[7]=(_Float16)v1.w;
        *(half8*)(Wsm + (size_t)((c * 2 + nb) * 64 + l) * 8) = hb;
    }
    if (tid < 128) {
        cst[tid] = 0.f; cst[128 + tid] = 0.f; cst[256 + tid] = 0.f; cst[384 + tid] = 0.f;
    }

    const int pb = tid >> 3, pc = tid & 7;
    const int gc = w * 8 + pc;
    const float bI = bih[gc]        + bhh[gc];
    const float bF = bih[512 + gc]  + bhh[512 + gc];
    const float bG = bih[1024 + gc] + bhh[1024 + gc];
    const float bO = bih[1536 + gc] + bhh[1536 + gc];
    __syncthreads();

    const int coff = (wv + 2) & 7;     // wave's chunk offset (h chunks)
    // ring u64 col for this wave's fragment A; fragment B at +64
    const int rcol = coff * 8 + l4 * 2;

    auto wfrag = [&](int c, int nb) -> half8 {
        return *(const half8*)(Wsm + (size_t)((c * 2 + nb) * 64 + l) * 8);
    };
    auto raddr = [&](int chain, int slot) -> size_t {
        return ((size_t)(slot * 4 + chain) * 16 + l15) * 128 + rcol;
    };
    auto rld = [&](size_t i) -> u64 {
        return __hip_atomic_load(ring + i, __ATOMIC_RELAXED, __HIP_MEMORY_SCOPE_AGENT);
    };

    // validate 4 prefetched u64 (2 fragments); on tag mismatch, re-poll.
    const u64 TM = 0x0001000100010001ULL;
    auto consume = [&](u64 a0, u64 a1, u64 b0, u64 b1, size_t ia, unsigned par_,
                       half8& ha, half8& hb) {
        const u64 ex = par_ ? TM : 0ULL;
        bool ok = ((a0 & TM) == ex) && ((a1 & TM) == ex) &&
                  ((b0 & TM) == ex) && ((b1 & TM) == ex);
        while (!__all(ok)) {
            if (!ok) {
                a0 = rld(ia); a1 = rld(ia + 1); b0 = rld(ia + 64); b1 = rld(ia + 65);
                ok = ((a0 & TM) == ex) && ((a1 & TM) == ex) &&
                     ((b0 & TM) == ex) && ((b1 & TM) == ex);
            }
        }
        union { u64 u[2]; half8 h; } ca, cb;
        ca.u[0] = a0; ca.u[1] = a1; cb.u[0] = b0; cb.u[1] = b1;
        ha = ca.h; hb = cb.h;
    };

    // ---- prefetch register state (constant-indexed after full unroll) ----
    float4 xa0[4], xa1[4];
    u64 h1p[4][4];                 // h(t-1) prefetch per chain
    u64 h32p[4][4];                // h(t-32) prefetch per chain

    // prologue: x for t=0, all chains
#pragma unroll
    for (int g = 0; g < 4; ++g) {
        if (wv < 6) {
            const int gb = g * 16 + l15;
            const int k0 = wv * 32 + l4 * 8;
            const float* xs = x + ((size_t)(gb * 3 + (k0 >> 6)) * 256 + ((k0 >> 3) & 7)) * 256;
            xa0[g] = ((const float4*)xs)[0];
            xa1[g] = ((const float4*)xs)[1];
        }
    }

    for (int t = 0; t < T_; ++t) {
#pragma unroll
        for (int g = 0; g < 4; ++g) {
            const int par = g & 1;      // (t*4+g)&1 == g&1
            f32x4 acc0 = {0.f,0.f,0.f,0.f}, acc1 = {0.f,0.f,0.f,0.f};

            // [A] x part (prefetched regs)
            if (wv < 6) {
                half8 a;
                a[0]=(_Float16)xa0[g].x; a[1]=(_Float16)xa0[g].y;
                a[2]=(_Float16)xa0[g].z; a[3]=(_Float16)xa0[g].w;
                a[4]=(_Float16)xa1[g].x; a[5]=(_Float16)xa1[g].y;
                a[6]=(_Float16)xa1[g].z; a[7]=(_Float16)xa1[g].w;
                acc0 = __builtin_amdgcn_mfma_f32_16x16x32_f16(a, wfrag(wv,0), acc0, 0,0,0);
                acc1 = __builtin_amdgcn_mfma_f32_16x16x32_f16(a, wfrag(wv,1), acc1, 0,0,0);
            }
            // [B] h(t-32) part (prefetched; tag-validated, never stalls in practice)
            if (t >= 32) {
                half8 ha, hb;
                consume(h32p[g][0], h32p[g][1], h32p[g][2], h32p[g][3],
                        raddr(g, (t - 32) & 63), ((t - 32) >> 6) & 1, ha, hb);
                acc0 = __builtin_amdgcn_mfma_f32_16x16x32_f16(ha, wfrag(6+coff,0),  acc0, 0,0,0);
                acc1 = __builtin_amdgcn_mfma_f32_16x16x32_f16(ha, wfrag(6+coff,1),  acc1, 0,0,0);
                acc0 = __builtin_amdgcn_mfma_f32_16x16x32_f16(hb, wfrag(14+coff,0), acc0, 0,0,0);
                acc1 = __builtin_amdgcn_mfma_f32_16x16x32_f16(hb, wfrag(14+coff,1), acc1, 0,0,0);
            }
            // [C] h(t-1) (prefetched 2 sub-steps ago; tag-validated)
            if (t >= 1) {
                half8 ha, hb;
                consume(h1p[g][0], h1p[g][1], h1p[g][2], h1p[g][3],
                        raddr(g, (t - 1) & 63), ((t - 1) >> 6) & 1, ha, hb);
                acc0 = __builtin_amdgcn_mfma_f32_16x16x32_f16(ha, wfrag(22+coff,0), acc0, 0,0,0);
                acc1 = __builtin_amdgcn_mfma_f32_16x16x32_f16(ha, wfrag(22+coff,1), acc1, 0,0,0);
                acc0 = __builtin_amdgcn_mfma_f32_16x16x32_f16(hb, wfrag(30+coff,0), acc0, 0,0,0);
                acc1 = __builtin_amdgcn_mfma_f32_16x16x32_f16(hb, wfrag(30+coff,1), acc1, 0,0,0);
            }

            // [D] partials -> LDS (parity double-buffer)
            {
                float* Pw = Psm + (size_t)((par * 8 + wv) * 16) * 33;
#pragma unroll
                for (int r = 0; r < 4; ++r) {
                    Pw[(l4 * 4 + r) * 33 + l15]      = acc0[r];
                    Pw[(l4 * 4 + r) * 33 + 16 + l15] = acc1[r];
                }
            }

            // [P1] h(t-1) prefetch for chain gp=(g+2)&3 (published 2 sub-steps ago)
            {
                const int gp = (g + 2) & 3;
                const int tp = (gp > g) ? (t - 1) : t;   // step being prefetched
                if (tp >= 0) {
                    const size_t ia = raddr(gp, tp & 63);
                    h1p[gp][0] = rld(ia);     h1p[gp][1] = rld(ia + 1);
                    h1p[gp][2] = rld(ia + 64); h1p[gp][3] = rld(ia + 65);
                }
            }
            // [P2] next-step prefetch for this chain: x(t+1) and h(t+1-32)
            if (t + 1 < T_) {
                if (wv < 6) {
                    const int gb = g * 16 + l15;
                    const int yn = (t + 1) >> 5, xcn = (t + 1) & 31;
                    const int k0 = wv * 32 + l4 * 8;
                    const float* xs = x + ((size_t)(gb * 3 + (k0 >> 6)) * 256
                                           + yn * 8 + ((k0 >> 3) & 7)) * 256 + xcn * 8;
                    xa0[g] = ((const float4*)xs)[0];
                    xa1[g] = ((const float4*)xs)[1];
                }
                if (t + 1 >= 32) {
                    const size_t ia = raddr(g, (t + 1 - 32) & 63);
                    h32p[g][0] = rld(ia);      h32p[g][1] = rld(ia + 1);
                    h32p[g][2] = rld(ia + 64); h32p[g][3] = rld(ia + 65);
                }
            }

            __syncthreads();   // [E] one barrier per sub-step

            // [F] pointwise + tagged publish (waves 0-1); waves 2-7 run ahead
            if (tid < 128) {
                float gi = bI, gf = bF, gg = bG, go = bO;
#pragma unroll
                for (int q = 0; q < 8; ++q) {
                    const float* Pq = Psm + ((size_t)((par * 8 + q) * 16 + pb)) * 33 + pc * 4;
                    gi += Pq[0]; gf += Pq[1]; gg += Pq[2]; go += Pq[3];
                }
                const float cprev = cst[g * 128 + tid];
                const float si = 1.f / (1.f + __expf(-gi));
                const float sf = 1.f / (1.f + __expf(-gf));
                const float so = 1.f / (1.f + __expf(-go));
                const float tg = 2.f / (1.f + __expf(-2.f * gg)) - 1.f;
                const float cn = sf * cprev + si * tg;
                const float th = 2.f / (1.f + __expf(-2.f * cn)) - 1.f;
                const float hn = so * th;
                cst[g * 128 + tid] = cn;

                union { _Float16 f; unsigned short s; } cv; cv.f = (_Float16)hn;
                unsigned hb16 = ((unsigned)cv.s & ~1u) | (unsigned)((t >> 6) & 1);
                unsigned other = (unsigned)__shfl_xor((int)hb16, 1);
                unsigned pairv = (pc & 1) ? ((other & 0xffffu) | (hb16 << 16))
                                          : ((hb16 & 0xffffu) | (other << 16));
                unsigned hi = (unsigned)__shfl_xor((int)pairv, 2);
                if ((pc & 3) == 0) {
                    u64 val = (u64)pairv | ((u64)hi << 32);
                    const size_t idx = ((size_t)((t & 63) * 4 + g) * 16 + pb) * 128
                                     + w * 2 + (pc >> 2);
                    __hip_atomic_store(ring + idx, val, __ATOMIC_RELAXED,
                                       __HIP_MEMORY_SCOPE_AGENT);
                }
                out[(size_t)(g * 16 + pb) * (T_ * 512) + (size_t)t * 512 + gc] = hn;
            }
        }
    }
}

extern "C" void kernel_launch(void* const* d_in, const int* in_sizes, int n_in,
                              void* d_out, int out_size, void* d_ws, size_t ws_size,
                              hipStream_t stream) {
    const float* x   = (const float*)d_in[0];
    const float* Wih = (const float*)d_in[1];
    const float* Whh = (const float*)d_in[2];
    const float* bih = (const float*)d_in[3];
    const float* bhh = (const float*)d_in[4];
    float* out = (float*)d_out;

    u64* ring = (u64*)d_ws;   // 64*4*16*128 u64 = 4 MB

    // LSB pattern 1 everywhere != gen-0 parity 0
    hipMemsetAsync(ring, 0x01, 64ull * 4 * 16 * 128 * 8, stream);

    (void)hipFuncSetAttribute((const void*)lstm_persist,
                              hipFuncAttributeMaxDynamicSharedMemorySize, LDS_ALL);

    hipLaunchKernelGGL(lstm_persist, dim3(64), dim3(512), LDS_ALL, stream,
                       x, Wih, Whh, bih, bhh, out, ring);
}